// Round 3
// baseline (1526.663 us; speedup 1.0000x reference)
//
#include <hip/hip_runtime.h>
#include <stdint.h>

#define NN 8192
#define FF 128
#define DD 4
#define BM 64
#define BN 128
#define BK 64
#define KSPLIT 8
#define KCHUNK (NN / KSPLIT)  // 1024
#define NT (NN / BM)          // 128 M-tiles

typedef __attribute__((ext_vector_type(8))) short bf16x8;
typedef __attribute__((ext_vector_type(4))) float f32x4;

__device__ __forceinline__ unsigned short f2bf(float f) {
  uint32_t u = __float_as_uint(f);
  u += 0x7fffu + ((u >> 16) & 1u);  // round-to-nearest-even
  return (unsigned short)(u >> 16);
}

__device__ __forceinline__ void gld_lds16(const void* g, void* l) {
  auto gp = reinterpret_cast<const uint32_t __attribute__((address_space(1)))*>(
      reinterpret_cast<uintptr_t>(g));
  auto lp = reinterpret_cast<uint32_t __attribute__((address_space(3)))*>(
      reinterpret_cast<uintptr_t>(l));
  __builtin_amdgcn_global_load_lds(gp, lp, 16, 0, 0);
}

// ---------------- in_feat [NN][FF] fp32 -> featT [FF][NN] bf16 ----------------
__global__ void cvt_feat(const float* __restrict__ x, unsigned short* __restrict__ xT) {
  __shared__ float tile[32][33];
  int m0 = blockIdx.x * 32;
  int n0 = blockIdx.y * 32;
  int tx = threadIdx.x & 31, ty = threadIdx.x >> 5;
#pragma unroll
  for (int r = 0; r < 4; ++r) {
    int mm = ty + r * 8;
    tile[mm][tx] = x[(size_t)(m0 + mm) * FF + n0 + tx];
  }
  __syncthreads();
#pragma unroll
  for (int r = 0; r < 4; ++r) {
    int nn = ty + r * 8;
    xT[(size_t)(n0 + nn) * NN + m0 + tx] = f2bf(tile[tx][nn]);
  }
}

// ---------------- fused GEMM hop + split-K last-block finalize ----------------
// FIRST: A comes in fp32 (adjf), converted in-kernel, bf16 copy streamed to adjb_out.
// !FIRST: A comes in bf16 (adjb_in) via global_load_lds.
// Finalize (last block per M-tile): feat = sum_s parts[s]; h (+)= theta[hop]*feat;
// featT_out = bf16(feat^T) unless last hop.
template <bool FIRST>
__global__ __launch_bounds__(256, 4) void gemm_poly(
    const float* __restrict__ adjf,
    const unsigned short* __restrict__ adjb_in,
    unsigned short* __restrict__ adjb_out,
    const unsigned short* __restrict__ featT,
    float* __restrict__ parts,
    float* __restrict__ h,
    unsigned short* __restrict__ featT_out,
    const float* __restrict__ theta,
    unsigned int* __restrict__ cnt,
    int hop) {
  __shared__ unsigned short sA[BM * BK];  // 8 KB, XOR-swizzled 16B chunks
  __shared__ unsigned short sB[BN * BK];  // 16 KB
  __shared__ float ttile[BM][33];         // finalize transpose staging
  __shared__ int sFlag;

  const int bx = blockIdx.x;
  const int ks = bx & (KSPLIT - 1);  // split-K group (adjacent blocks same tile)
  const int mt = bx >> 3;
  const int m0 = mt * BM;
  const int k0 = ks * KCHUNK;

  const int t = threadIdx.x;
  const int w = t >> 6;
  const int l = t & 63;

  // B staging: 16 KB = 4 waves x 4 insts x 1 KB. Stored chunk c of row r holds
  // global chunk c^(r&7); LDS side linear for the DMA.
  uint32_t offB[4];
  unsigned short* ldsB[4];
#pragma unroll
  for (int j = 0; j < 4; ++j) {
    uint32_t obase = (uint32_t)w * 4096u + (uint32_t)j * 1024u;
    uint32_t o = obase + (uint32_t)l * 16u;
    uint32_t r = o >> 7;
    uint32_t c = (o >> 4) & 7u;
    uint32_t gc = c ^ (r & 7u);
    ldsB[j] = sB + (obase >> 1);
    offB[j] = r * (uint32_t)NN + (uint32_t)k0 + gc * 8u;
  }

  // A staging (!FIRST): 8 KB = 4 waves x 2 insts x 1 KB.
  uint32_t offA[2];
  unsigned short* ldsA[2];
#pragma unroll
  for (int j = 0; j < 2; ++j) {
    uint32_t obase = (uint32_t)w * 2048u + (uint32_t)j * 1024u;
    uint32_t o = obase + (uint32_t)l * 16u;
    uint32_t r = o >> 7;
    uint32_t c = (o >> 4) & 7u;
    uint32_t gc = c ^ (r & 7u);
    ldsA[j] = sA + (obase >> 1);
    offA[j] = (uint32_t)(m0 + r) * (uint32_t)NN + (uint32_t)k0 + gc * 8u;
  }

  // A staging (FIRST): thread t loads 16 consecutive fp32 of row ar.
  const int ar = t >> 2;
  const int ac4 = t & 3;
  uint32_t aoff = (uint32_t)(m0 + ar) * (uint32_t)NN + (uint32_t)k0 + (uint32_t)ac4 * 16u;
  const int ch0 = (2 * ac4) ^ (ar & 7);  // stored chunk for global chunk 2*ac4
  unsigned short* wA0 = sA + ar * BK + ch0 * 8;
  unsigned short* wA1 = sA + ar * BK + (ch0 ^ 1) * 8;

  f32x4 acc[2][4];
#pragma unroll
  for (int i = 0; i < 2; ++i)
#pragma unroll
    for (int j = 0; j < 4; ++j) acc[i][j] = (f32x4){0.f, 0.f, 0.f, 0.f};

  const int wm = w >> 1;  // 2x2 wave grid, wave tile 32x64
  const int wn = w & 1;
  const int lr = l & 15;
  const int lq = l >> 4;

  for (int kt = 0; kt < KCHUNK; kt += BK) {
    if (FIRST) {
      float4 v0 = *(const float4*)(adjf + aoff);
      float4 v1 = *(const float4*)(adjf + aoff + 4);
      float4 v2 = *(const float4*)(adjf + aoff + 8);
      float4 v3 = *(const float4*)(adjf + aoff + 12);
      union { unsigned short us[8]; uint4 v; } p0, p1;
      p0.us[0] = f2bf(v0.x); p0.us[1] = f2bf(v0.y); p0.us[2] = f2bf(v0.z); p0.us[3] = f2bf(v0.w);
      p0.us[4] = f2bf(v1.x); p0.us[5] = f2bf(v1.y); p0.us[6] = f2bf(v1.z); p0.us[7] = f2bf(v1.w);
      p1.us[0] = f2bf(v2.x); p1.us[1] = f2bf(v2.y); p1.us[2] = f2bf(v2.z); p1.us[3] = f2bf(v2.w);
      p1.us[4] = f2bf(v3.x); p1.us[5] = f2bf(v3.y); p1.us[6] = f2bf(v3.z); p1.us[7] = f2bf(v3.w);
      *(uint4*)wA0 = p0.v;
      *(uint4*)wA1 = p1.v;
      *(uint4*)(adjb_out + aoff) = p0.v;      // linear bf16 copy for hops 1-3
      *(uint4*)(adjb_out + aoff + 8) = p1.v;
      aoff += BK;
    } else {
#pragma unroll
      for (int j = 0; j < 2; ++j) gld_lds16(adjb_in + offA[j], ldsA[j]);
#pragma unroll
      for (int j = 0; j < 2; ++j) offA[j] += BK;
    }
#pragma unroll
    for (int j = 0; j < 4; ++j) gld_lds16(featT + offB[j], ldsB[j]);
#pragma unroll
    for (int j = 0; j < 4; ++j) offB[j] += BK;
    __syncthreads();
#pragma unroll
    for (int kk = 0; kk < 2; ++kk) {
      bf16x8 af[2], bfr[4];
#pragma unroll
      for (int tm = 0; tm < 2; ++tm) {
        int row = wm * 32 + tm * 16 + lr;
        int ch = (kk * 4 + lq) ^ (row & 7);
        af[tm] = *(const bf16x8*)(sA + row * BK + ch * 8);
      }
#pragma unroll
      for (int tn = 0; tn < 4; ++tn) {
        int row = wn * 64 + tn * 16 + lr;
        int ch = (kk * 4 + lq) ^ (row & 7);
        bfr[tn] = *(const bf16x8*)(sB + row * BK + ch * 8);
      }
#pragma unroll
      for (int tm = 0; tm < 2; ++tm)
#pragma unroll
        for (int tn = 0; tn < 4; ++tn)
          acc[tm][tn] = __builtin_amdgcn_mfma_f32_16x16x32_bf16(
              af[tm], bfr[tn], acc[tm][tn], 0, 0, 0);
    }
    __syncthreads();
  }

  // store split-K partials (disjoint per ks)
  float* pout = parts + (size_t)ks * NN * FF;
#pragma unroll
  for (int tm = 0; tm < 2; ++tm) {
#pragma unroll
    for (int tn = 0; tn < 4; ++tn) {
      int m = m0 + wm * 32 + tm * 16 + lq * 4;
      int n = wn * 64 + tn * 16 + lr;
#pragma unroll
      for (int r = 0; r < 4; ++r)
        pout[(size_t)(m + r) * FF + n] = acc[tm][tn][r];
    }
  }

  // -------- last-block-done finalize --------
  __threadfence();   // release our partial stores device-wide
  __syncthreads();
  if (t == 0)
    sFlag = (atomicAdd(&cnt[hop * NT + mt], 1u) == KSPLIT - 1) ? 1 : 0;
  __syncthreads();
  if (!sFlag) return;
  __threadfence();   // acquire before reading other blocks' partials

  const float th = theta[hop];
  const bool accum = (hop > 0);
  const bool writeT = (hop < DD - 1);
  const int tx = t & 31;
  const int ty = t >> 5;

#pragma unroll
  for (int sc = 0; sc < 4; ++sc) {  // 32-feature column chunks
    int n = sc * 32 + tx;
#pragma unroll
    for (int mp = 0; mp < 8; ++mp) {
      int m = mp * 8 + ty;
      size_t idx = (size_t)(m0 + m) * FF + n;
      float a = 0.f;
#pragma unroll
      for (int s = 0; s < KSPLIT; ++s) a += parts[(size_t)s * NN * FF + idx];
      float hv = th * a;
      if (accum) hv += h[idx];
      h[idx] = hv;
      if (writeT) ttile[m][tx] = a;
    }
    if (writeT) {
      __syncthreads();
#pragma unroll
      for (int np = 0; np < 4; ++np) {
        int j = np * 8 + ty;  // feature within chunk
        uint32_t u = (uint32_t)f2bf(ttile[2 * tx][j]) |
                     ((uint32_t)f2bf(ttile[2 * tx + 1][j]) << 16);
        *(uint32_t*)(featT_out + (size_t)(sc * 32 + j) * NN + m0 + 2 * tx) = u;
      }
      __syncthreads();
    }
  }
}

extern "C" void kernel_launch(void* const* d_in, const int* in_sizes, int n_in,
                              void* d_out, int out_size, void* d_ws, size_t ws_size,
                              hipStream_t stream) {
  const float* adj = (const float*)d_in[0];
  const float* in_feat = (const float*)d_in[1];
  const float* theta = (const float*)d_in[3];  // d_in[2] (lapl) unused by forward
  float* h = (float*)d_out;

  char* ws = (char*)d_ws;
  unsigned short* adjb = (unsigned short*)ws;                          // 128 MiB
  unsigned short* fTa = (unsigned short*)(ws + (size_t)NN * NN * 2);   // 2 MiB
  unsigned short* fTb = fTa + (size_t)FF * NN;                         // 2 MiB
  float* parts = (float*)(fTb + (size_t)FF * NN);                      // 32 MiB
  unsigned int* cnt = (unsigned int*)(parts + (size_t)KSPLIT * NN * FF);  // 2 KB

  hipMemsetAsync(cnt, 0, (size_t)DD * NT * sizeof(unsigned int), stream);
  cvt_feat<<<dim3(NN / 32, FF / 32), 256, 0, stream>>>(in_feat, fTa);

  // hop 0: fp32 adj in, converts + streams adjb, writes h and fTb
  gemm_poly<true><<<NT * KSPLIT, 256, 0, stream>>>(
      adj, nullptr, adjb, fTa, parts, h, fTb, theta, cnt, 0);

  unsigned short* fin = fTb;
  unsigned short* fout = fTa;
  for (int hop = 1; hop < DD; ++hop) {
    gemm_poly<false><<<NT * KSPLIT, 256, 0, stream>>>(
        nullptr, adjb, nullptr, fin, parts, h, fout, theta, cnt, hop);
    unsigned short* tmp = fin; fin = fout; fout = tmp;
  }
}